// Round 4
// baseline (86.007 us; speedup 1.0000x reference)
//
#include <hip/hip_runtime.h>

#define BATCH     256
#define INPUT_DIM 4096
#define SOMA      2048
#define BRANCHES  16
#define NDEND     32768
#define SAMPLE    32

#define THREADS   1024
#define B_T       4
#define NTILES    8                          // 32 batch rows per block
#define TILE_F    (INPUT_DIM * B_T)          // floats per LDS buffer (64 KiB)

typedef unsigned int u32;
typedef __attribute__((address_space(1))) const u32 gu32;
typedef __attribute__((address_space(3))) u32 lu32;

__device__ __forceinline__ void async_load16(const float* g, float* l) {
    __builtin_amdgcn_global_load_lds((const gu32*)g, (lu32*)l, 16, 0, 0);
}

// ---------------- transpose x[256][4096] -> xT[4096][256] ----------------
#define TT 64
__global__ __launch_bounds__(256)
void transpose_kernel(const float* __restrict__ x, float* __restrict__ xT)
{
    __shared__ float tile[TT][TT + 1];
    const int tx = threadIdx.x & (TT - 1);
    const int ty = threadIdx.x >> 6;              // 0..3
    const int gi = blockIdx.x * TT;               // input_dim base
    const int gb = blockIdx.y * TT;               // batch base

    #pragma unroll
    for (int r = 0; r < TT; r += 4)               // read coalesced along i
        tile[ty + r][tx] = x[(size_t)(gb + ty + r) * INPUT_DIM + gi + tx];
    __syncthreads();
    #pragma unroll
    for (int r = 0; r < TT; r += 4)               // write coalesced along b
        xT[(size_t)(gi + ty + r) * BATCH + gb + tx] = tile[tx][ty + r];
}

// ---------------- main fused kernel ----------------
__global__ __launch_bounds__(THREADS)
void dendrite_kernel(const float* __restrict__ xT,   // [INPUT_DIM][BATCH]
                     const int*   __restrict__ didx,
                     const float* __restrict__ sw,
                     const float* __restrict__ sb,
                     const float* __restrict__ cw,
                     const float* __restrict__ somab,
                     float* __restrict__ soma_out,   // [BATCH][SOMA]
                     float* __restrict__ dend_out)   // [BATCH][NDEND]
{
    extern __shared__ float xs[];                 // 2 buffers x 64 KiB

    const int t  = threadIdx.x;
    const int dc = blockIdx.x;                    // dendrite chunk (32)
    const int bs = blockIdx.y;                    // batch super-tile (8)
    const int d  = dc * THREADS + t;              // this thread's dendrite

    // ---- idx/w once into registers: 16 + 32 VGPRs ----
    uint  off[SAMPLE / 2];
    float w[SAMPLE];
    {
        const int4*   ip = (const int4*)  (didx + (size_t)d * SAMPLE);
        const float4* wp = (const float4*)(sw   + (size_t)d * SAMPLE);
        #pragma unroll
        for (int g = 0; g < SAMPLE / 4; ++g) {
            const int4   iv = ip[g];
            const float4 wv = wp[g];
            off[2*g]   = ((uint)iv.x << 4) | ((uint)iv.y << 20);   // byte offsets i*16
            off[2*g+1] = ((uint)iv.z << 4) | ((uint)iv.w << 20);
            w[4*g] = wv.x; w[4*g+1] = wv.y; w[4*g+2] = wv.z; w[4*g+3] = wv.w;
        }
    }
    const float bias = sb[d];
    const float cwv  = cw[d];
    const int   n    = d >> 4;
    const float sbi  = somab[n];
    const int   b00  = bs * (B_T * NTILES);

    // ---- stage tile 0 (async, zero VGPR) ----
    #pragma unroll
    for (int r = 0; r < INPUT_DIM / THREADS; ++r) {     // 4 per thread
        const int i = r * THREADS + t;
        async_load16(xT + (size_t)i * BATCH + b00, xs + i * B_T);
    }

    for (int k = 0; k < NTILES; ++k) {
        const int b0 = b00 + k * B_T;
        const char* buf = (const char*)(xs + (k & 1) * TILE_F);

        asm volatile("s_waitcnt vmcnt(0)" ::: "memory");   // stage(k) landed
        __syncthreads();                                   // everyone: buf ready, prev reads done

        if (k + 1 < NTILES) {                              // async stage(k+1) -> other buffer
            float* nbuf = xs + ((k + 1) & 1) * TILE_F;
            const int nb0 = b0 + B_T;
            #pragma unroll
            for (int r = 0; r < INPUT_DIM / THREADS; ++r) {
                const int i = r * THREADS + t;
                async_load16(xT + (size_t)i * BATCH + nb0, nbuf + i * B_T);
            }
        }

        // ---- gather + FMA (regs + LDS only) ----
        float4 acc = {0.f, 0.f, 0.f, 0.f};
        #pragma unroll
        for (int g = 0; g < SAMPLE / 2; ++g) {
            const uint pr = off[g];
            const float4 xv0 = *(const float4*)(buf + (pr & 0xFFFFu));
            const float4 xv1 = *(const float4*)(buf + (pr >> 16));
            const float w0 = w[2*g], w1 = w[2*g+1];
            acc.x += xv0.x * w0; acc.y += xv0.y * w0;
            acc.z += xv0.z * w0; acc.w += xv0.w * w0;
            acc.x += xv1.x * w1; acc.y += xv1.y * w1;
            acc.z += xv1.z * w1; acc.w += xv1.w * w1;
        }

        // ---- epilogue ----
        const float a[B_T] = {acc.x, acc.y, acc.z, acc.w};
        float part[B_T];
        #pragma unroll
        for (int bb = 0; bb < B_T; ++bb) {
            const float pre = a[bb] + bias;
            const float act = (pre >= 0.f) ? pre : 0.1f * pre;
            dend_out[(size_t)(b0 + bb) * NDEND + d] = act;     // coalesced
            part[bb] = act * cwv;
        }
        #pragma unroll
        for (int m = 1; m < BRANCHES; m <<= 1) {
            #pragma unroll
            for (int bb = 0; bb < B_T; ++bb)
                part[bb] += __shfl_xor(part[bb], m);
        }
        if ((t & (BRANCHES - 1)) == 0) {
            #pragma unroll
            for (int bb = 0; bb < B_T; ++bb) {
                const float pre = part[bb] + sbi;
                soma_out[(size_t)(b0 + bb) * SOMA + n] = (pre >= 0.f) ? pre : 0.1f * pre;
            }
        }
    }
}

extern "C" void kernel_launch(void* const* d_in, const int* in_sizes, int n_in,
                              void* d_out, int out_size, void* d_ws, size_t ws_size,
                              hipStream_t stream) {
    const float* x     = (const float*)d_in[0];
    const int*   didx  = (const int*)  d_in[1];
    const float* sw    = (const float*)d_in[2];
    const float* sb    = (const float*)d_in[3];
    const float* cw    = (const float*)d_in[4];
    const float* somab = (const float*)d_in[5];

    float* soma_out = (float*)d_out;                     // [256][2048]
    float* dend_out = soma_out + (size_t)BATCH * SOMA;   // [256][32768]
    float* xT       = (float*)d_ws;                      // [4096][256] = 4 MiB scratch

    static bool attr_set = false;                        // idempotent host-side attr
    if (!attr_set) {
        hipFuncSetAttribute((const void*)dendrite_kernel,
                            hipFuncAttributeMaxDynamicSharedMemorySize,
                            2 * TILE_F * (int)sizeof(float));
        attr_set = true;
    }

    dim3 tgrid(INPUT_DIM / TT, BATCH / TT);              // (64, 4)
    transpose_kernel<<<tgrid, 256, 0, stream>>>(x, xT);

    dim3 grid(NDEND / THREADS, BATCH / (B_T * NTILES));  // (32, 8) = 256 blocks, 1/CU
    dendrite_kernel<<<grid, THREADS, 2 * TILE_F * sizeof(float), stream>>>(
        xT, didx, sw, sb, cw, somab, soma_out, dend_out);
}